// Round 13
// baseline (635.199 us; speedup 1.0000x reference)
//
#include <hip/hip_runtime.h>
#include <math.h>

// ---------------- problem constants ----------------
#define H 256
#define S_STEPS 4
#define B_RXN 512
#define N_MOLS 2048          // B*S
#define ATOMS_PER_MOL 32
#define N_ATOMS 65536        // N_MOLS*32
#define N_BONDS 131072
#define NBP1 131073          // N_BONDS+1
#define MAX_NB 6
#define ATOM_FDIM 133
#define BOND_FDIM 147
#define DEPTH 3
#define N_ITERS 3

typedef unsigned short bf16u;
typedef __attribute__((ext_vector_type(8))) short short8v;  // 8 bf16 = 4 VGPR
typedef __attribute__((ext_vector_type(4))) float f32x4;

__device__ __forceinline__ float b2f(bf16u u) {
    union { unsigned int i; float f; } c; c.i = ((unsigned int)u) << 16; return c.f;
}
__device__ __forceinline__ bf16u f2b(float f) {
    union { float f; unsigned int i; } c; c.f = f;
    unsigned int i = c.i;
    return (bf16u)((i + 0x7FFFu + ((i >> 16) & 1u)) >> 16);   // RNE
}
__device__ __forceinline__ unsigned int relu2bf(unsigned int w) {
    unsigned int lo = w & 0xFFFFu, hi = w >> 16;
    if (lo & 0x8000u) lo = 0u;
    if (hi & 0x8000u) hi = 0u;
    return lo | (hi << 16);
}

// ============ dense MFMA GEMM (bond/atom): BM=256, 512 thr / 8 waves ============
// 2-barrier step structure (round-10/12 proven), 32 MFMA per wave per step.
// Wave w: rows (w&3)*64..+63, cols (w>>2)*128..+127.
// MODE 0 (WI):   A = FB16 [M,160];              epi: INP = bf16(acc)
// MODE 1 (MW):   A = msg-source [M,256] (opt. relu in staging); epi: MW = bf16(acc)
// MODE 2 (ATOM): A = [FA16 160 | AMSG 256] (KP=416); epi: bf16 relu(acc+bias)
template<int MODE, bool RELUA>
__global__ __launch_bounds__(512) void dense_gemm_k(
    const bf16u* __restrict__ A1,
    const bf16u* __restrict__ A2,     // MODE2 only
    const bf16u* __restrict__ WT,     // [256][KP] bf16
    const float* __restrict__ bias,   // MODE2 only
    bf16u* __restrict__ outb,
    int M)
{
    constexpr int KP = (MODE == 0) ? 160 : ((MODE == 1) ? 256 : 416);
    __shared__ bf16u As[256][40];
    __shared__ bf16u Bs[256][40];

    const int tid = threadIdx.x;
    const int lane = tid & 63, w = tid >> 6;      // 8 waves
    const int wr = w & 3, wc = w >> 2;            // 4 row-groups x 2 col-groups
    const int m0 = blockIdx.x * 256;
    const int ar = tid >> 1, q16 = (tid & 1) * 16; // A stage: row, 16-col half
    const int br = tid >> 1, bh = (tid & 1) * 16;  // B stage: row, k-half
    const int arow = m0 + ar;
    const bool rok = arow < M;
    const int lr = lane & 15, lk = (lane >> 4) * 8;
    const uint4 z4 = {0u, 0u, 0u, 0u};

    f32x4 acc[4][8];
    const f32x4 zf = {0.f, 0.f, 0.f, 0.f};
    #pragma unroll
    for (int i = 0; i < 4; ++i)
        #pragma unroll
        for (int j = 0; j < 8; ++j) acc[i][j] = zf;

    for (int k0 = 0; k0 < KP; k0 += 32) {
        // ---- stage A: two contiguous uint4 per thread (32B half-row) ----
        const int kc = k0 + q16;          // 16-aligned; never straddles 160 (160%16==0)
        uint4 va0, va1;
        if (MODE == 2) {
            const bf16u* p = (kc < 160) ? (A1 + (size_t)arow * 160 + kc)
                                        : (A2 + (size_t)arow * 256 + (kc - 160));
            va0 = *(const uint4*)p;
            va1 = *(const uint4*)(p + 8);
        } else {
            constexpr int LDA = (MODE == 0) ? 160 : 256;
            if (rok) {
                const bf16u* p = A1 + (size_t)arow * LDA + kc;
                va0 = *(const uint4*)p;
                va1 = *(const uint4*)(p + 8);
            } else { va0 = z4; va1 = z4; }
        }
        if (RELUA) {
            va0.x = relu2bf(va0.x); va0.y = relu2bf(va0.y);
            va0.z = relu2bf(va0.z); va0.w = relu2bf(va0.w);
            va1.x = relu2bf(va1.x); va1.y = relu2bf(va1.y);
            va1.z = relu2bf(va1.z); va1.w = relu2bf(va1.w);
        }
        *(uint4*)&As[ar][q16] = va0;
        *(uint4*)&As[ar][q16 + 8] = va1;
        // ---- stage B: 2 uint4 per thread ----
        {
            const bf16u* bp = WT + (size_t)br * KP + k0 + bh;
            uint4 b0 = *(const uint4*)(bp);
            uint4 b1 = *(const uint4*)(bp + 8);
            *(uint4*)&Bs[br][bh] = b0;
            *(uint4*)&Bs[br][bh + 8] = b1;
        }
        __syncthreads();

        short8v a[4], b[8];
        #pragma unroll
        for (int mf = 0; mf < 4; ++mf)
            a[mf] = *(const short8v*)&As[wr * 64 + mf * 16 + lr][lk];
        #pragma unroll
        for (int nf = 0; nf < 8; ++nf)
            b[nf] = *(const short8v*)&Bs[wc * 128 + nf * 16 + lr][lk];
        #pragma unroll
        for (int mf = 0; mf < 4; ++mf)
            #pragma unroll
            for (int nf = 0; nf < 8; ++nf)
                acc[mf][nf] = __builtin_amdgcn_mfma_f32_16x16x32_bf16(
                    a[mf], b[nf], acc[mf][nf], 0, 0, 0);
        __syncthreads();
    }

    const int rbase = (lane >> 4) * 4;
    #pragma unroll
    for (int mf = 0; mf < 4; ++mf) {
        #pragma unroll
        for (int nf = 0; nf < 8; ++nf) {
            const int col = wc * 128 + nf * 16 + lr;
            #pragma unroll
            for (int r = 0; r < 4; ++r) {
                const int row = m0 + wr * 64 + mf * 16 + rbase + r;
                if (row >= M) continue;
                float v = acc[mf][nf][r];
                const size_t off = (size_t)row * H + col;
                if (MODE == 2) {
                    v += bias[col];
                    outb[off] = f2b(fmaxf(v, 0.f));
                } else {
                    outb[off] = f2b(v);
                }
            }
        }
    }
}

// ---- combine: msg[b] = relu(inp[b] + AP[b2a[b]] - MW[b2revb[b]]), row 0 = 0 ----
__global__ __launch_bounds__(256) void combine_k(
    const bf16u* __restrict__ inp, const bf16u* __restrict__ AP,
    const bf16u* __restrict__ MW,
    const int* __restrict__ b2a, const int* __restrict__ b2revb,
    bf16u* __restrict__ msg)
{
    int idx = blockIdx.x * 256 + threadIdx.x;
    if (idx >= NBP1 * 32) return;
    int b = idx >> 5, c = (idx & 31) * 8;
    bf16u* op = msg + (size_t)b * H + c;
    if (b == 0) {
        *(uint4*)op = make_uint4(0u, 0u, 0u, 0u);
        return;
    }
    int a = b2a[b], rb = b2revb[b];
    uint4 ui = *(const uint4*)(inp + (size_t)b * H + c);
    uint4 up = *(const uint4*)(AP + (size_t)a * H + c);
    uint4 um = *(const uint4*)(MW + (size_t)rb * H + c);
    uint4 o;
    unsigned int* pi = &ui.x; unsigned int* pp = &up.x;
    unsigned int* pm = &um.x; unsigned int* po = &o.x;
    #pragma unroll
    for (int t = 0; t < 4; ++t) {
        float lo = b2f((bf16u)(pi[t] & 0xFFFFu)) + b2f((bf16u)(pp[t] & 0xFFFFu))
                 - b2f((bf16u)(pm[t] & 0xFFFFu));
        float hi = b2f((bf16u)(pi[t] >> 16)) + b2f((bf16u)(pp[t] >> 16))
                 - b2f((bf16u)(pm[t] >> 16));
        lo = fmaxf(lo, 0.f); hi = fmaxf(hi, 0.f);
        po[t] = (unsigned int)f2b(lo) | ((unsigned int)f2b(hi) << 16);
    }
    *(uint4*)op = o;
}

// ============ mid-phase MFMA linear, BM=64 x BN=64 (round-9 proven) ============
template<bool BIAS>
__global__ __launch_bounds__(256) void lin64_k(
    const float* __restrict__ A1, int lda1, int KA1,
    const float* __restrict__ A2, int lda2,
    const bf16u* __restrict__ WT, int ldw,
    const float* __restrict__ bias,
    float* __restrict__ C, int ldc, int K)
{
    __shared__ bf16u As[64][40];
    __shared__ bf16u Bs[64][40];
    const int tid = threadIdx.x;
    const int lane = tid & 63, w = tid >> 6;
    const int m0 = blockIdx.x * 64;
    const int col0 = blockIdx.y * 64;
    const int ar = tid >> 2, kq8 = (tid & 3) * 8;
    const int lr = lane & 15, lk = (lane >> 4) * 8;

    f32x4 acc[4];
    const f32x4 zf = {0.f, 0.f, 0.f, 0.f};
    #pragma unroll
    for (int j = 0; j < 4; ++j) acc[j] = zf;

    for (int k0 = 0; k0 < K; k0 += 32) {
        const float* src = (k0 < KA1)
            ? (A1 + (size_t)(m0 + ar) * lda1 + k0 + kq8)
            : (A2 + (size_t)(m0 + ar) * lda2 + (k0 - KA1) + kq8);
        float4 f0 = *(const float4*)src;
        float4 f1 = *(const float4*)(src + 4);
        ushort4 s0, s1;
        s0.x = f2b(f0.x); s0.y = f2b(f0.y); s0.z = f2b(f0.z); s0.w = f2b(f0.w);
        s1.x = f2b(f1.x); s1.y = f2b(f1.y); s1.z = f2b(f1.z); s1.w = f2b(f1.w);
        *(ushort4*)&As[ar][kq8] = s0;
        *(ushort4*)&As[ar][kq8 + 4] = s1;
        *(uint4*)&Bs[ar][kq8] = *(const uint4*)(WT + (size_t)(col0 + ar) * ldw + k0 + kq8);
        __syncthreads();

        short8v a = *(const short8v*)&As[w * 16 + lr][lk];
        short8v b[4];
        #pragma unroll
        for (int nf = 0; nf < 4; ++nf)
            b[nf] = *(const short8v*)&Bs[nf * 16 + lr][lk];
        #pragma unroll
        for (int nf = 0; nf < 4; ++nf)
            acc[nf] = __builtin_amdgcn_mfma_f32_16x16x32_bf16(a, b[nf], acc[nf], 0, 0, 0);
        __syncthreads();
    }

    const int rbase = (lane >> 4) * 4;
    #pragma unroll
    for (int nf = 0; nf < 4; ++nf) {
        const int col = col0 + nf * 16 + lr;
        #pragma unroll
        for (int r = 0; r < 4; ++r) {
            const int row = m0 + w * 16 + rbase + r;
            float v = acc[nf][r];
            if (BIAS) v += bias[col];
            C[(size_t)row * ldc + col] = v;
        }
    }
}

__device__ __forceinline__ float sigm(float x) { return 1.f / (1.f + expf(-x)); }

// ============ fused LSTM gates GEMM + pointwise (round-11 proven) ============
__global__ __launch_bounds__(256) void gates_lstm_k(
    const float* __restrict__ QSTAR,  // [M,512]
    const float* __restrict__ Hc,     // [M,256]
    const float* __restrict__ Cc,     // [M,256]
    const bf16u* __restrict__ WT,     // [1024][768]
    const float* __restrict__ bias,   // [1024]
    float* __restrict__ Hn,
    float* __restrict__ Cn,
    int M)
{
    __shared__ bf16u As[64][40];
    __shared__ bf16u Bs[64][40];
    const int tid = threadIdx.x;
    const int lane = tid & 63, w = tid >> 6;      // 4 waves, 16 rows each
    const int m0 = blockIdx.x * 64;
    const int db = blockIdx.y;                    // d-slice [db*16, +16)
    const int ar = tid >> 2, q8 = (tid & 3) * 8;
    const int lr = lane & 15, lk = (lane >> 4) * 8;

    f32x4 acc[4];                                 // one per gate
    const f32x4 zf = {0.f, 0.f, 0.f, 0.f};
    #pragma unroll
    for (int g = 0; g < 4; ++g) acc[g] = zf;

    for (int k0 = 0; k0 < 768; k0 += 32) {
        const float* src = (k0 < 512)
            ? QSTAR + (size_t)(m0 + ar) * 512 + k0 + q8
            : Hc + (size_t)(m0 + ar) * 256 + (k0 - 512) + q8;
        float4 f0 = *(const float4*)src;
        float4 f1 = *(const float4*)(src + 4);
        ushort4 s0, s1;
        s0.x = f2b(f0.x); s0.y = f2b(f0.y); s0.z = f2b(f0.z); s0.w = f2b(f0.w);
        s1.x = f2b(f1.x); s1.y = f2b(f1.y); s1.z = f2b(f1.z); s1.w = f2b(f1.w);
        *(ushort4*)&As[ar][q8] = s0;
        *(ushort4*)&As[ar][q8 + 4] = s1;
        {
            int rho = tid >> 2;
            int g = rho >> 4, cn = rho & 15;
            *(uint4*)&Bs[rho][q8] =
                *(const uint4*)(WT + (size_t)(g * 256 + db * 16 + cn) * 768 + k0 + q8);
        }
        __syncthreads();
        short8v a = *(const short8v*)&As[w * 16 + lr][lk];
        #pragma unroll
        for (int g = 0; g < 4; ++g) {
            short8v b = *(const short8v*)&Bs[g * 16 + lr][lk];
            acc[g] = __builtin_amdgcn_mfma_f32_16x16x32_bf16(a, b, acc[g], 0, 0, 0);
        }
        __syncthreads();
    }

    const int rbase = (lane >> 4) * 4;
    const int d = db * 16 + lr;
    const float bi = bias[d], bf = bias[256 + d], bg = bias[512 + d], bo = bias[768 + d];
    #pragma unroll
    for (int r = 0; r < 4; ++r) {
        const int row = m0 + w * 16 + rbase + r;
        float i_ = acc[0][r] + bi;
        float f_ = acc[1][r] + bf;
        float g_ = acc[2][r] + bg;
        float o_ = acc[3][r] + bo;
        float cv = sigm(f_) * Cc[(size_t)row * 256 + d] + sigm(i_) * tanhf(g_);
        Cn[(size_t)row * 256 + d] = cv;
        Hn[(size_t)row * 256 + d] = sigm(o_) * tanhf(cv);
    }
}

// ---- iteration-0 LSTM: q_star=h=c=0 -> gates=bias (exact). Broadcast h0,c0 to all rows ----
__global__ __launch_bounds__(256) void lstm0_bcast_k(const float* __restrict__ bias,
                                                     float* __restrict__ Hn,
                                                     float* __restrict__ Cn, int M)
{
    int idx = blockIdx.x * 256 + threadIdx.x;
    if (idx >= M * 256) return;
    int d = idx & 255;
    float c0 = sigm(bias[d]) * tanhf(bias[512 + d]);
    float h0 = sigm(bias[768 + d]) * tanhf(c0);
    Cn[idx] = c0;
    Hn[idx] = h0;
}

// ---------------- prep kernels ----------------
__global__ __launch_bounds__(256) void prep_wt_k(const float* __restrict__ W,
                                                 bf16u* __restrict__ WT, int K, int KP)
{
    int idx = blockIdx.x * 256 + threadIdx.x;
    if (idx >= 256 * KP) return;
    int n = idx / KP, k = idx - n * KP;
    WT[idx] = (k < K) ? f2b(W[(size_t)k * H + n]) : (bf16u)0;
}

__global__ __launch_bounds__(256) void prep_wto_k(const float* __restrict__ Wo,
                                                  bf16u* __restrict__ WT)
{
    int idx = blockIdx.x * 256 + threadIdx.x;
    if (idx >= 256 * 416) return;
    int n = idx / 416, k = idx - n * 416;
    float v = 0.f;
    if (k < ATOM_FDIM) v = Wo[(size_t)k * H + n];
    else if (k >= 160) v = Wo[(size_t)(ATOM_FDIM + k - 160) * H + n];
    WT[idx] = f2b(v);
}

// merged mid-phase weight prep (single dispatch)
#define SZ_WTG   786432    // [1024][768]
#define SZ_WTNC  131072    // [256][512]
#define SZ_WTPQS 196608    // [768][256]
#define SZ_WTN1  262144    // [256][1024]
#define SZ_WTGC  131072    // [256][512]
__global__ __launch_bounds__(256) void prep_mid_k(
    const float* __restrict__ Wih_n, const float* __restrict__ Whh_n,
    const float* __restrict__ Wih_g, const float* __restrict__ Whh_g,
    const float* __restrict__ ncW,  const float* __restrict__ Wnn0,
    const float* __restrict__ Wnn0s, const float* __restrict__ Wnn1,
    const float* __restrict__ gcW,  const float* __restrict__ b_nn0s,
    bf16u* __restrict__ WTG_N, bf16u* __restrict__ WTG_G,
    bf16u* __restrict__ WT_NC, bf16u* __restrict__ WT_PQS,
    bf16u* __restrict__ WT_N1, bf16u* __restrict__ WT_GC,
    float* __restrict__ BIAS_PQS)
{
    int idx = blockIdx.x * 256 + threadIdx.x;
    if (idx < SZ_WTG) {
        int n = idx / 768, k = idx - n * 768;
        WTG_N[idx] = f2b(k < 512 ? Wih_n[(size_t)n * 512 + k] : Whh_n[(size_t)n * 256 + (k - 512)]);
        return;
    }
    idx -= SZ_WTG;
    if (idx < SZ_WTG) {
        int n = idx / 768, k = idx - n * 768;
        WTG_G[idx] = f2b(k < 512 ? Wih_g[(size_t)n * 512 + k] : Whh_g[(size_t)n * 256 + (k - 512)]);
        return;
    }
    idx -= SZ_WTG;
    if (idx < SZ_WTNC) {
        int n = idx / 512, k = idx - n * 512;
        WT_NC[idx] = f2b(ncW[(size_t)k * 256 + n]);
        return;
    }
    idx -= SZ_WTNC;
    if (idx < SZ_WTPQS) {
        int n = idx / 256, k = idx - n * 256;
        float v;
        if (n < 256)      v = Wnn0[(size_t)k * 256 + n];
        else if (n < 512) v = Wnn0[(size_t)(256 + k) * 256 + (n - 256)];
        else              v = Wnn0s[(size_t)k * 256 + (n - 512)];
        WT_PQS[idx] = f2b(v);
        return;
    }
    idx -= SZ_WTPQS;
    if (idx < SZ_WTN1) {
        int n = idx / 1024, k = idx - n * 1024;
        WT_N1[idx] = f2b(Wnn1[(size_t)k * 256 + n]);
        return;
    }
    idx -= SZ_WTN1;
    if (idx < SZ_WTGC) {
        int n = idx / 512, k = idx - n * 512;
        WT_GC[idx] = f2b(gcW[(size_t)k * 256 + n]);
        return;
    }
    idx -= SZ_WTGC;
    if (idx < 768) BIAS_PQS[idx] = (idx < 512) ? 0.f : b_nn0s[idx - 512];
}
#define PREP_MID_TOTAL (2 * SZ_WTG + SZ_WTNC + SZ_WTPQS + SZ_WTN1 + SZ_WTGC + 768)

// pack f32 features -> bf16 rows padded to 160 (4 cols per thread)
__global__ __launch_bounds__(256) void prep_feat16_k(const float* __restrict__ F,
                                                     bf16u* __restrict__ O,
                                                     int rows, int K)
{
    int idx = blockIdx.x * 256 + threadIdx.x;
    if (idx >= rows * 40) return;
    int r = idx / 40, c4 = (idx - r * 40) * 4;
    const float* src = F + (size_t)r * K + c4;
    ushort4 o;
    o.x = (c4 + 0 < K) ? f2b(src[0]) : (bf16u)0;
    o.y = (c4 + 1 < K) ? f2b(src[1]) : (bf16u)0;
    o.z = (c4 + 2 < K) ? f2b(src[2]) : (bf16u)0;
    o.w = (c4 + 3 < K) ? f2b(src[3]) : (bf16u)0;
    *(ushort4*)(O + (size_t)r * 160 + c4) = o;
}

// ---------------- small kernels ----------------
__global__ __launch_bounds__(256) void gather6_bf16_k(const bf16u* __restrict__ msg,
                                                      const int* __restrict__ a2b,
                                                      bf16u* __restrict__ outb)
{
    int idx = blockIdx.x * 256 + threadIdx.x;
    if (idx >= N_ATOMS * (H / 8)) return;
    int na = idx >> 5, c = idx & 31;
    const int* nb = a2b + (size_t)na * MAX_NB;
    float s[8] = {0.f, 0.f, 0.f, 0.f, 0.f, 0.f, 0.f, 0.f};
    #pragma unroll
    for (int j = 0; j < MAX_NB; ++j) {
        uint4 u = *(const uint4*)(msg + (size_t)nb[j] * H + c * 8);
        s[0] += b2f((bf16u)(u.x & 0xFFFFu)); s[1] += b2f((bf16u)(u.x >> 16));
        s[2] += b2f((bf16u)(u.y & 0xFFFFu)); s[3] += b2f((bf16u)(u.y >> 16));
        s[4] += b2f((bf16u)(u.z & 0xFFFFu)); s[5] += b2f((bf16u)(u.z >> 16));
        s[6] += b2f((bf16u)(u.w & 0xFFFFu)); s[7] += b2f((bf16u)(u.w >> 16));
    }
    uint4 o;
    o.x = (unsigned int)f2b(s[0]) | ((unsigned int)f2b(s[1]) << 16);
    o.y = (unsigned int)f2b(s[2]) | ((unsigned int)f2b(s[3]) << 16);
    o.z = (unsigned int)f2b(s[4]) | ((unsigned int)f2b(s[5]) << 16);
    o.w = (unsigned int)f2b(s[6]) | ((unsigned int)f2b(s[7]) << 16);
    *(uint4*)(outb + (size_t)na * H + c * 8) = o;
}

// feat bf16 (BF16F) or f32; h/q_star f32
template<bool BF16F>
__global__ __launch_bounds__(256) void s2s_attn_k(const void* __restrict__ featv,
                                                  const float* __restrict__ h,
                                                  float* __restrict__ q_star, int Nn)
{
    int m = blockIdx.x;
    int t = threadIdx.x;
    int lane = t & 63, wave = t >> 6;
    __shared__ float sc[32];
    const bf16u* fb = (const bf16u*)featv;
    const float* ff = (const float*)featv;
    const size_t fbase = (size_t)m * Nn * H;
    const float* hm = h + (size_t)m * H;
    for (int n = wave; n < Nn; n += 4) {
        float p = 0.f;
        if (BF16F) {
            ushort4 u = *(const ushort4*)(fb + fbase + (size_t)n * H + lane * 4);
            const float4 h4 = *(const float4*)(hm + lane * 4);
            p = b2f(u.x) * h4.x + b2f(u.y) * h4.y + b2f(u.z) * h4.z + b2f(u.w) * h4.w;
        } else {
            const float* fr = ff + fbase + (size_t)n * H;
            #pragma unroll
            for (int u = 0; u < 4; ++u) p += fr[lane * 4 + u] * hm[lane * 4 + u];
        }
        #pragma unroll
        for (int o = 32; o >= 1; o >>= 1) p += __shfl_xor(p, o);
        if (lane == 0) sc[n] = p;
    }
    __syncthreads();
    float mx = -1e30f;
    for (int n = 0; n < Nn; ++n) mx = fmaxf(mx, sc[n]);
    float ssum = 0.f, r = 0.f;
    for (int n = 0; n < Nn; ++n) {
        float a = expf(sc[n] - mx);
        ssum += a;
        float fv = BF16F ? b2f(fb[fbase + (size_t)n * H + t]) : ff[fbase + (size_t)n * H + t];
        r += a * fv;
    }
    r /= ssum;
    q_star[(size_t)m * (2 * H) + t] = hm[t];
    q_star[(size_t)m * (2 * H) + H + t] = r;
}

// X[b,s1,s2,:] from packed PQS [2048][768]: P = +0, Q = +256, SO = +512
__global__ __launch_bounds__(256) void build_x_k(const float* __restrict__ PQS,
                                                 const float* __restrict__ b0,
                                                 float* __restrict__ X)
{
    int idx = blockIdx.x * 256 + threadIdx.x;
    if (idx >= B_RXN * S_STEPS * S_STEPS * H) return;
    int d  = idx & 255;
    int s2 = (idx >> 8) & 3;
    int s1 = (idx >> 10) & 3;
    int b  = idx >> 12;
    float v;
    if (s1 == s2) v = PQS[((size_t)(b * S_STEPS + s1)) * 768 + 512 + d];
    else v = PQS[((size_t)(b * S_STEPS + s1)) * 768 + d]
           + PQS[((size_t)(b * S_STEPS + s2)) * 768 + 256 + d] + b0[d];
    X[idx] = v;
}

// ---------------- launch ----------------
extern "C" void kernel_launch(void* const* d_in, const int* in_sizes, int n_in,
                              void* d_out, int out_size, void* d_ws, size_t ws_size,
                              hipStream_t stream)
{
    const float* f_atoms   = (const float*)d_in[0];
    const float* f_bonds   = (const float*)d_in[1];
    const int*   a2b       = (const int*)d_in[2];
    const int*   b2a       = (const int*)d_in[3];
    const int*   b2revb    = (const int*)d_in[4];
    const float* W_i       = (const float*)d_in[5];
    const float* W_h       = (const float*)d_in[6];
    const float* W_o       = (const float*)d_in[7];
    const float* b_o       = (const float*)d_in[8];
    const float* W_nn0     = (const float*)d_in[9];
    const float* b_nn0     = (const float*)d_in[10];
    const float* W_nn0s    = (const float*)d_in[11];
    const float* b_nn0s    = (const float*)d_in[12];
    const float* W_nn1     = (const float*)d_in[13];
    const float* b_nn1     = (const float*)d_in[14];
    const float* lstm_n_Wih = (const float*)d_in[15];
    const float* lstm_n_Whh = (const float*)d_in[16];
    const float* lstm_n_b   = (const float*)d_in[17];
    const float* node_cond_W = (const float*)d_in[18];
    const float* node_cond_b = (const float*)d_in[19];
    const float* lstm_g_Wih = (const float*)d_in[20];
    const float* lstm_g_Whh = (const float*)d_in[21];
    const float* lstm_g_b   = (const float*)d_in[22];
    const float* graph_cond_W = (const float*)d_in[23];
    const float* graph_cond_b = (const float*)d_in[24];
    float* out = (float*)d_out;

    // ---- workspace layout (~235 MB) ----
    const size_t SZB = (size_t)NBP1 * H * sizeof(bf16u);    // 67,109,376 B
    char* base = (char*)d_ws;
    bf16u* INP  = (bf16u*)(base);                            // [NBP1,H]
    bf16u* MSG  = (bf16u*)(base + SZB);                      // [NBP1,H]
    bf16u* MW   = (bf16u*)(base + 2 * SZB);                  // [NBP1,H]
    bf16u* AMSG = (bf16u*)(base + 3 * SZB);                  // [N_ATOMS,H]
    bf16u* WT_I = (bf16u*)(base + 3 * SZB + 33554432);       // [256][160]
    bf16u* WT_H = (bf16u*)(base + 3 * SZB + 33636352);       // [256][256]
    bf16u* WT_O = (bf16u*)(base + 3 * SZB + 33767424);       // [256][416]
    // aliases:
    bf16u* FB16 = MW;                                        // before 1st MW
    bf16u* FA16 = MW;                                        // after last combine
    bf16u* ATOMH16 = (bf16u*)(base);                         // bf16 feat, alias INP (dead)
    float* SMALL = (float*)(base + SZB);                     // f32 scratch, alias MSG (dead)
    float* HN     = SMALL + 2097152;                         // [2048,256] (ping A)
    float* CN     = SMALL + 2621440;                         // [2048,256] (ping A)
    float* QSTARN = SMALL + 3145728;                         // [2048,512]
    float* MOL    = SMALL + 4194304;                         // [2048,256]
    float* PQS    = SMALL + 4718592;                         // [2048,768]
    float* XBUF   = SMALL + 6291456;                         // [8192,256]
    float* STEPS  = SMALL + 8388608;                         // [2048,256]
    float* HG     = SMALL + 8912896;                         // [512,256] (ping A)
    float* CG     = SMALL + 9043968;                         // [512,256] (ping A)
    float* QSTARG = SMALL + 9175040;                         // [512,512]
    float* HN2    = SMALL + 10485760;                        // [2048,256] (pong B)
    float* CN2    = SMALL + 11010048;                        // [2048,256] (pong B)
    float* HG2    = SMALL + 11534336;                        // [512,256]  (pong B)
    float* CG2    = SMALL + 11665408;                        // [512,256]  (pong B)
    char* sm2 = base + 2 * SZB + 25165824;                   // MW dead zone
    bf16u* WTG_N   = (bf16u*)(sm2);                  // [1024][768]
    bf16u* WTG_G   = (bf16u*)(sm2 + 1572864);        // [1024][768]
    bf16u* WT_NC   = (bf16u*)(sm2 + 3145728);        // [256][512]
    bf16u* WT_PQS  = (bf16u*)(sm2 + 3407872);        // [768][256]
    bf16u* WT_N1   = (bf16u*)(sm2 + 3801088);        // [256][1024]
    bf16u* WT_GC   = (bf16u*)(sm2 + 4325376);        // [256][512]
    float* BIAS_PQS = (float*)(sm2 + 4587520);       // [768]

    dim3 blk(256), blk5(512);
    const int MB_BOND = (NBP1 + 255) / 256;   // 513
    const int MB_ATOM = N_ATOMS / 256;        // 256
    const int G_GATH = (N_ATOMS * (H / 8) + 255) / 256;
    const int G_COMB = (NBP1 * 32 + 255) / 256;

    // 0. weight + input prep
    prep_wt_k<<<(256 * 160 + 255) / 256, blk, 0, stream>>>(W_i, WT_I, BOND_FDIM, 160);
    prep_wt_k<<<(256 * 256 + 255) / 256, blk, 0, stream>>>(W_h, WT_H, H, 256);
    prep_wto_k<<<(256 * 416 + 255) / 256, blk, 0, stream>>>(W_o, WT_O);
    prep_feat16_k<<<(int)(((size_t)NBP1 * 40 + 255) / 256), blk, 0, stream>>>(
        f_bonds, FB16, NBP1, BOND_FDIM);

    // 1. INP = FB16 @ W_i
    dense_gemm_k<0, false><<<MB_BOND, blk5, 0, stream>>>(
        FB16, nullptr, WT_I, nullptr, INP, NBP1);

    // 2. depth loop
    dense_gemm_k<1, true><<<MB_BOND, blk5, 0, stream>>>(
        INP, nullptr, WT_H, nullptr, MW, NBP1);
    gather6_bf16_k<<<G_GATH, blk, 0, stream>>>(MW, a2b, AMSG);
    combine_k<<<G_COMB, blk, 0, stream>>>(INP, AMSG, MW, b2a, b2revb, MSG);
    dense_gemm_k<1, false><<<MB_BOND, blk5, 0, stream>>>(
        MSG, nullptr, WT_H, nullptr, MW, NBP1);
    gather6_bf16_k<<<G_GATH, blk, 0, stream>>>(MW, a2b, AMSG);
    combine_k<<<G_COMB, blk, 0, stream>>>(INP, AMSG, MW, b2a, b2revb, MSG);

    // 3. nei = gather6(final MSG)
    gather6_bf16_k<<<G_GATH, blk, 0, stream>>>(MSG, a2b, AMSG);

    // 3b. packed f_atoms + merged mid-phase weight prep (MW region dead)
    prep_feat16_k<<<(N_ATOMS * 40 + 255) / 256, blk, 0, stream>>>(
        f_atoms, FA16, N_ATOMS, ATOM_FDIM);
    prep_mid_k<<<(PREP_MID_TOTAL + 255) / 256, blk, 0, stream>>>(
        lstm_n_Wih, lstm_n_Whh, lstm_g_Wih, lstm_g_Whh,
        node_cond_W, W_nn0, W_nn0s, W_nn1, graph_cond_W, b_nn0s,
        WTG_N, WTG_G, WT_NC, WT_PQS, WT_N1, WT_GC, BIAS_PQS);

    // 4. atom_h = relu([f_atoms, nei] @ W_o + b_o) -> ATOMH16 bf16
    dense_gemm_k<2, false><<<MB_ATOM, blk5, 0, stream>>>(
        FA16, AMSG, WT_O, b_o, ATOMH16, N_ATOMS);

    // 5. node Set2Set over [2048, 32, 256]
    {
        lstm0_bcast_k<<<(N_MOLS * H + 255) / 256, blk, 0, stream>>>(lstm_n_b, HN, CN, N_MOLS);
        s2s_attn_k<true><<<N_MOLS, blk, 0, stream>>>(ATOMH16, HN, QSTARN, ATOMS_PER_MOL);
        float *hc = HN, *cc = CN, *hn = HN2, *cn = CN2;
        for (int it = 1; it < N_ITERS; ++it) {
            gates_lstm_k<<<dim3(N_MOLS / 64, 16), blk, 0, stream>>>(
                QSTARN, hc, cc, WTG_N, lstm_n_b, hn, cn, N_MOLS);
            s2s_attn_k<true><<<N_MOLS, blk, 0, stream>>>(ATOMH16, hn, QSTARN, ATOMS_PER_MOL);
            float* t;
            t = hc; hc = hn; hn = t;
            t = cc; cc = cn; cn = t;
        }
    }
    lin64_k<true><<<dim3(N_MOLS / 64, 4), blk, 0, stream>>>(
        QSTARN, 2 * H, 2 * H, QSTARN, 2 * H, WT_NC, 2 * H, node_cond_b, MOL, H, 2 * H);

    // 6. NN attention over steps (fused P|Q|SO GEMM)
    lin64_k<true><<<dim3(N_MOLS / 64, 12), blk, 0, stream>>>(
        MOL, H, H, MOL, H, WT_PQS, H, BIAS_PQS, PQS, 3 * H, H);
    build_x_k<<<(B_RXN * 16 * H) / 256, blk, 0, stream>>>(PQS, b_nn0, XBUF);
    lin64_k<true><<<dim3(N_MOLS / 64, 4), blk, 0, stream>>>(
        XBUF, S_STEPS * H, S_STEPS * H, XBUF, S_STEPS * H, WT_N1, S_STEPS * H, b_nn1,
        STEPS, H, S_STEPS * H);

    // 7. graph Set2Set over [512, 4, 256]
    {
        lstm0_bcast_k<<<(B_RXN * H + 255) / 256, blk, 0, stream>>>(lstm_g_b, HG, CG, B_RXN);
        s2s_attn_k<false><<<B_RXN, blk, 0, stream>>>(STEPS, HG, QSTARG, S_STEPS);
        float *hc = HG, *cc = CG, *hn = HG2, *cn = CG2;
        for (int it = 1; it < N_ITERS; ++it) {
            gates_lstm_k<<<dim3(B_RXN / 64, 16), blk, 0, stream>>>(
                QSTARG, hc, cc, WTG_G, lstm_g_b, hn, cn, B_RXN);
            s2s_attn_k<false><<<B_RXN, blk, 0, stream>>>(STEPS, hn, QSTARG, S_STEPS);
            float* t;
            t = hc; hc = hn; hn = t;
            t = cc; cc = cn; cn = t;
        }
    }

    // 8. out
    lin64_k<true><<<dim3(B_RXN / 64, 4), blk, 0, stream>>>(
        QSTARG, 2 * H, 2 * H, QSTARG, 2 * H, WT_GC, 2 * H, graph_cond_b, out, H, 2 * H);
}

// Round 14
// 569.856 us; speedup vs baseline: 1.1147x; 1.1147x over previous
//
#include <hip/hip_runtime.h>
#include <math.h>

// ---------------- problem constants ----------------
#define H 256
#define S_STEPS 4
#define B_RXN 512
#define N_MOLS 2048          // B*S
#define ATOMS_PER_MOL 32
#define N_ATOMS 65536        // N_MOLS*32
#define N_BONDS 131072
#define NBP1 131073          // N_BONDS+1
#define MAX_NB 6
#define ATOM_FDIM 133
#define BOND_FDIM 147
#define DEPTH 3
#define N_ITERS 3

typedef unsigned short bf16u;
typedef __attribute__((ext_vector_type(8))) short short8v;  // 8 bf16 = 4 VGPR
typedef __attribute__((ext_vector_type(4))) float f32x4;

__device__ __forceinline__ float b2f(bf16u u) {
    union { unsigned int i; float f; } c; c.i = ((unsigned int)u) << 16; return c.f;
}
__device__ __forceinline__ bf16u f2b(float f) {
    union { float f; unsigned int i; } c; c.f = f;
    unsigned int i = c.i;
    return (bf16u)((i + 0x7FFFu + ((i >> 16) & 1u)) >> 16);   // RNE
}
__device__ __forceinline__ unsigned int relu2bf(unsigned int w) {
    unsigned int lo = w & 0xFFFFu, hi = w >> 16;
    if (lo & 0x8000u) lo = 0u;
    if (hi & 0x8000u) hi = 0u;
    return lo | (hi << 16);
}

// ============ dense MFMA GEMM (bond/atom): BM=128, 512 thr / 8 waves (round-12 proven) ======
// MODE 0 (WI):   A = FB16 [M,160];              epi: INP = bf16(acc)
// MODE 1 (MW):   A = msg-source [M,256] (opt. relu in staging); epi: MW = bf16(acc)
// MODE 2 (ATOM): A = [FA16 160 | AMSG 256] (KP=416); epi: bf16 relu(acc+bias)
template<int MODE, bool RELUA>
__global__ __launch_bounds__(512) void dense_gemm_k(
    const bf16u* __restrict__ A1,
    const bf16u* __restrict__ A2,     // MODE2 only
    const bf16u* __restrict__ WT,     // [256][KP] bf16
    const float* __restrict__ bias,   // MODE2 only
    bf16u* __restrict__ outb,
    int M)
{
    constexpr int KP = (MODE == 0) ? 160 : ((MODE == 1) ? 256 : 416);
    __shared__ bf16u As[128][40];
    __shared__ bf16u Bs[256][40];

    const int tid = threadIdx.x;
    const int lane = tid & 63, w = tid >> 6;      // 8 waves
    const int wr = w >> 2, wc = w & 3;            // 2 x 4 wave grid
    const int m0 = blockIdx.x * 128;
    const int ar = tid >> 2, q8 = (tid & 3) * 8;  // A stage: row, k-chunk
    const int br = tid >> 1, bh = (tid & 1) * 16; // B stage: row, k-half
    const int arow = m0 + ar;
    const bool rok = arow < M;
    const int lr = lane & 15, lk = (lane >> 4) * 8;
    const uint4 z4 = {0u, 0u, 0u, 0u};

    f32x4 acc[4][4];
    const f32x4 zf = {0.f, 0.f, 0.f, 0.f};
    #pragma unroll
    for (int i = 0; i < 4; ++i)
        #pragma unroll
        for (int j = 0; j < 4; ++j) acc[i][j] = zf;

    for (int k0 = 0; k0 < KP; k0 += 32) {
        // ---- stage A: one uint4 per thread (contiguous) ----
        const int kc = k0 + q8;
        uint4 va;
        if (MODE == 2) {
            va = (kc < 160) ? *(const uint4*)(A1 + (size_t)arow * 160 + kc)
                            : *(const uint4*)(A2 + (size_t)arow * 256 + (kc - 160));
        } else {
            constexpr int LDA = (MODE == 0) ? 160 : 256;
            va = rok ? *(const uint4*)(A1 + (size_t)arow * LDA + kc) : z4;
        }
        if (RELUA) {
            va.x = relu2bf(va.x); va.y = relu2bf(va.y);
            va.z = relu2bf(va.z); va.w = relu2bf(va.w);
        }
        *(uint4*)&As[ar][q8] = va;
        // ---- stage B: 2 uint4 per thread ----
        {
            const bf16u* bp = WT + (size_t)br * KP + k0 + bh;
            uint4 b0 = *(const uint4*)(bp);
            uint4 b1 = *(const uint4*)(bp + 8);
            *(uint4*)&Bs[br][bh] = b0;
            *(uint4*)&Bs[br][bh + 8] = b1;
        }
        __syncthreads();

        short8v a[4], b[4];
        #pragma unroll
        for (int mf = 0; mf < 4; ++mf)
            a[mf] = *(const short8v*)&As[wr * 64 + mf * 16 + lr][lk];
        #pragma unroll
        for (int nf = 0; nf < 4; ++nf)
            b[nf] = *(const short8v*)&Bs[wc * 64 + nf * 16 + lr][lk];
        #pragma unroll
        for (int mf = 0; mf < 4; ++mf)
            #pragma unroll
            for (int nf = 0; nf < 4; ++nf)
                acc[mf][nf] = __builtin_amdgcn_mfma_f32_16x16x32_bf16(
                    a[mf], b[nf], acc[mf][nf], 0, 0, 0);
        __syncthreads();
    }

    const int rbase = (lane >> 4) * 4;
    #pragma unroll
    for (int mf = 0; mf < 4; ++mf) {
        #pragma unroll
        for (int nf = 0; nf < 4; ++nf) {
            const int col = wc * 64 + nf * 16 + lr;
            #pragma unroll
            for (int r = 0; r < 4; ++r) {
                const int row = m0 + wr * 64 + mf * 16 + rbase + r;
                if (row >= M) continue;
                float v = acc[mf][nf][r];
                const size_t off = (size_t)row * H + col;
                if (MODE == 2) {
                    v += bias[col];
                    outb[off] = f2b(fmaxf(v, 0.f));
                } else {
                    outb[off] = f2b(v);
                }
            }
        }
    }
}

// ---- combine: msg[b] = relu(inp[b] + AP[b2a[b]] - MW[b2revb[b]]), row 0 = 0 ----
__global__ __launch_bounds__(256) void combine_k(
    const bf16u* __restrict__ inp, const bf16u* __restrict__ AP,
    const bf16u* __restrict__ MW,
    const int* __restrict__ b2a, const int* __restrict__ b2revb,
    bf16u* __restrict__ msg)
{
    int idx = blockIdx.x * 256 + threadIdx.x;
    if (idx >= NBP1 * 32) return;
    int b = idx >> 5, c = (idx & 31) * 8;
    bf16u* op = msg + (size_t)b * H + c;
    if (b == 0) {
        *(uint4*)op = make_uint4(0u, 0u, 0u, 0u);
        return;
    }
    int a = b2a[b], rb = b2revb[b];
    uint4 ui = *(const uint4*)(inp + (size_t)b * H + c);
    uint4 up = *(const uint4*)(AP + (size_t)a * H + c);
    uint4 um = *(const uint4*)(MW + (size_t)rb * H + c);
    uint4 o;
    unsigned int* pi = &ui.x; unsigned int* pp = &up.x;
    unsigned int* pm = &um.x; unsigned int* po = &o.x;
    #pragma unroll
    for (int t = 0; t < 4; ++t) {
        float lo = b2f((bf16u)(pi[t] & 0xFFFFu)) + b2f((bf16u)(pp[t] & 0xFFFFu))
                 - b2f((bf16u)(pm[t] & 0xFFFFu));
        float hi = b2f((bf16u)(pi[t] >> 16)) + b2f((bf16u)(pp[t] >> 16))
                 - b2f((bf16u)(pm[t] >> 16));
        lo = fmaxf(lo, 0.f); hi = fmaxf(hi, 0.f);
        po[t] = (unsigned int)f2b(lo) | ((unsigned int)f2b(hi) << 16);
    }
    *(uint4*)op = o;
}

// ============ mid-phase MFMA linear, BM=64 x BN=64, K-unroll x2 ============
// Requires K % 64 == 0 and KA1 % 64 == 0 (all call sites satisfy this).
template<bool BIAS>
__global__ __launch_bounds__(256) void lin64_k(
    const float* __restrict__ A1, int lda1, int KA1,
    const float* __restrict__ A2, int lda2,
    const bf16u* __restrict__ WT, int ldw,
    const float* __restrict__ bias,
    float* __restrict__ C, int ldc, int K)
{
    __shared__ bf16u As[64][72];
    __shared__ bf16u Bs[64][72];
    const int tid = threadIdx.x;
    const int lane = tid & 63, w = tid >> 6;
    const int m0 = blockIdx.x * 64;
    const int col0 = blockIdx.y * 64;
    const int ar = tid >> 2, kq8 = (tid & 3) * 8;
    const int lr = lane & 15, lk = (lane >> 4) * 8;

    f32x4 acc[4];
    const f32x4 zf = {0.f, 0.f, 0.f, 0.f};
    #pragma unroll
    for (int j = 0; j < 4; ++j) acc[j] = zf;

    for (int k0 = 0; k0 < K; k0 += 64) {
        const float* srcA = (k0 < KA1)
            ? (A1 + (size_t)(m0 + ar) * lda1 + k0)
            : (A2 + (size_t)(m0 + ar) * lda2 + (k0 - KA1));
        #pragma unroll
        for (int hh = 0; hh < 2; ++hh) {
            const float* p = srcA + hh * 32 + kq8;
            float4 f0 = *(const float4*)p;
            float4 f1 = *(const float4*)(p + 4);
            ushort4 s0, s1;
            s0.x = f2b(f0.x); s0.y = f2b(f0.y); s0.z = f2b(f0.z); s0.w = f2b(f0.w);
            s1.x = f2b(f1.x); s1.y = f2b(f1.y); s1.z = f2b(f1.z); s1.w = f2b(f1.w);
            *(ushort4*)&As[ar][hh * 32 + kq8] = s0;
            *(ushort4*)&As[ar][hh * 32 + kq8 + 4] = s1;
            *(uint4*)&Bs[ar][hh * 32 + kq8] =
                *(const uint4*)(WT + (size_t)(col0 + ar) * ldw + k0 + hh * 32 + kq8);
        }
        __syncthreads();

        short8v a0 = *(const short8v*)&As[w * 16 + lr][lk];
        short8v a1 = *(const short8v*)&As[w * 16 + lr][32 + lk];
        #pragma unroll
        for (int nf = 0; nf < 4; ++nf) {
            short8v b0 = *(const short8v*)&Bs[nf * 16 + lr][lk];
            acc[nf] = __builtin_amdgcn_mfma_f32_16x16x32_bf16(a0, b0, acc[nf], 0, 0, 0);
        }
        #pragma unroll
        for (int nf = 0; nf < 4; ++nf) {
            short8v b1 = *(const short8v*)&Bs[nf * 16 + lr][32 + lk];
            acc[nf] = __builtin_amdgcn_mfma_f32_16x16x32_bf16(a1, b1, acc[nf], 0, 0, 0);
        }
        __syncthreads();
    }

    const int rbase = (lane >> 4) * 4;
    #pragma unroll
    for (int nf = 0; nf < 4; ++nf) {
        const int col = col0 + nf * 16 + lr;
        #pragma unroll
        for (int r = 0; r < 4; ++r) {
            const int row = m0 + w * 16 + rbase + r;
            float v = acc[nf][r];
            if (BIAS) v += bias[col];
            C[(size_t)row * ldc + col] = v;
        }
    }
}

__device__ __forceinline__ float sigm(float x) { return 1.f / (1.f + expf(-x)); }

// ============ fused LSTM gates GEMM + pointwise, K-unroll x2 (K=768) ============
__global__ __launch_bounds__(256) void gates_lstm_k(
    const float* __restrict__ QSTAR,  // [M,512]
    const float* __restrict__ Hc,     // [M,256]
    const float* __restrict__ Cc,     // [M,256]
    const bf16u* __restrict__ WT,     // [1024][768]
    const float* __restrict__ bias,   // [1024]
    float* __restrict__ Hn,
    float* __restrict__ Cn,
    int M)
{
    __shared__ bf16u As[64][72];
    __shared__ bf16u Bs[64][72];
    const int tid = threadIdx.x;
    const int lane = tid & 63, w = tid >> 6;      // 4 waves, 16 rows each
    const int m0 = blockIdx.x * 64;
    const int db = blockIdx.y;                    // d-slice [db*16, +16)
    const int ar = tid >> 2, q8 = (tid & 3) * 8;
    const int lr = lane & 15, lk = (lane >> 4) * 8;

    f32x4 acc[4];                                 // one per gate
    const f32x4 zf = {0.f, 0.f, 0.f, 0.f};
    #pragma unroll
    for (int g = 0; g < 4; ++g) acc[g] = zf;

    const int rho = tid >> 2;                     // B-stage row 0..63
    const int bg = rho >> 4, bcn = rho & 15;      // gate, col-within-gate

    for (int k0 = 0; k0 < 768; k0 += 64) {        // 512 boundary is 64-aligned
        const float* srcA = (k0 < 512)
            ? QSTAR + (size_t)(m0 + ar) * 512 + k0
            : Hc + (size_t)(m0 + ar) * 256 + (k0 - 512);
        #pragma unroll
        for (int hh = 0; hh < 2; ++hh) {
            const float* p = srcA + hh * 32 + q8;
            float4 f0 = *(const float4*)p;
            float4 f1 = *(const float4*)(p + 4);
            ushort4 s0, s1;
            s0.x = f2b(f0.x); s0.y = f2b(f0.y); s0.z = f2b(f0.z); s0.w = f2b(f0.w);
            s1.x = f2b(f1.x); s1.y = f2b(f1.y); s1.z = f2b(f1.z); s1.w = f2b(f1.w);
            *(ushort4*)&As[ar][hh * 32 + q8] = s0;
            *(ushort4*)&As[ar][hh * 32 + q8 + 4] = s1;
            *(uint4*)&Bs[rho][hh * 32 + q8] =
                *(const uint4*)(WT + (size_t)(bg * 256 + db * 16 + bcn) * 768 + k0 + hh * 32 + q8);
        }
        __syncthreads();
        short8v a0 = *(const short8v*)&As[w * 16 + lr][lk];
        short8v a1 = *(const short8v*)&As[w * 16 + lr][32 + lk];
        #pragma unroll
        for (int g = 0; g < 4; ++g) {
            short8v b0 = *(const short8v*)&Bs[g * 16 + lr][lk];
            acc[g] = __builtin_amdgcn_mfma_f32_16x16x32_bf16(a0, b0, acc[g], 0, 0, 0);
        }
        #pragma unroll
        for (int g = 0; g < 4; ++g) {
            short8v b1 = *(const short8v*)&Bs[g * 16 + lr][32 + lk];
            acc[g] = __builtin_amdgcn_mfma_f32_16x16x32_bf16(a1, b1, acc[g], 0, 0, 0);
        }
        __syncthreads();
    }

    const int rbase = (lane >> 4) * 4;
    const int d = db * 16 + lr;
    const float bi = bias[d], bf = bias[256 + d], bg_ = bias[512 + d], bo = bias[768 + d];
    #pragma unroll
    for (int r = 0; r < 4; ++r) {
        const int row = m0 + w * 16 + rbase + r;
        float i_ = acc[0][r] + bi;
        float f_ = acc[1][r] + bf;
        float g_ = acc[2][r] + bg_;
        float o_ = acc[3][r] + bo;
        float cv = sigm(f_) * Cc[(size_t)row * 256 + d] + sigm(i_) * tanhf(g_);
        Cn[(size_t)row * 256 + d] = cv;
        Hn[(size_t)row * 256 + d] = sigm(o_) * tanhf(cv);
    }
}

// ---- iteration-0 LSTM: q_star=h=c=0 -> gates=bias (exact). Broadcast h0,c0 to all rows ----
__global__ __launch_bounds__(256) void lstm0_bcast_k(const float* __restrict__ bias,
                                                     float* __restrict__ Hn,
                                                     float* __restrict__ Cn, int M)
{
    int idx = blockIdx.x * 256 + threadIdx.x;
    if (idx >= M * 256) return;
    int d = idx & 255;
    float c0 = sigm(bias[d]) * tanhf(bias[512 + d]);
    float h0 = sigm(bias[768 + d]) * tanhf(c0);
    Cn[idx] = c0;
    Hn[idx] = h0;
}

// ---------------- prep kernels ----------------
__global__ __launch_bounds__(256) void prep_wt_k(const float* __restrict__ W,
                                                 bf16u* __restrict__ WT, int K, int KP)
{
    int idx = blockIdx.x * 256 + threadIdx.x;
    if (idx >= 256 * KP) return;
    int n = idx / KP, k = idx - n * KP;
    WT[idx] = (k < K) ? f2b(W[(size_t)k * H + n]) : (bf16u)0;
}

__global__ __launch_bounds__(256) void prep_wto_k(const float* __restrict__ Wo,
                                                  bf16u* __restrict__ WT)
{
    int idx = blockIdx.x * 256 + threadIdx.x;
    if (idx >= 256 * 416) return;
    int n = idx / 416, k = idx - n * 416;
    float v = 0.f;
    if (k < ATOM_FDIM) v = Wo[(size_t)k * H + n];
    else if (k >= 160) v = Wo[(size_t)(ATOM_FDIM + k - 160) * H + n];
    WT[idx] = f2b(v);
}

// merged mid-phase weight prep (single dispatch)
#define SZ_WTG   786432    // [1024][768]
#define SZ_WTNC  131072    // [256][512]
#define SZ_WTPQS 196608    // [768][256]
#define SZ_WTN1  262144    // [256][1024]
#define SZ_WTGC  131072    // [256][512]
__global__ __launch_bounds__(256) void prep_mid_k(
    const float* __restrict__ Wih_n, const float* __restrict__ Whh_n,
    const float* __restrict__ Wih_g, const float* __restrict__ Whh_g,
    const float* __restrict__ ncW,  const float* __restrict__ Wnn0,
    const float* __restrict__ Wnn0s, const float* __restrict__ Wnn1,
    const float* __restrict__ gcW,  const float* __restrict__ b_nn0s,
    bf16u* __restrict__ WTG_N, bf16u* __restrict__ WTG_G,
    bf16u* __restrict__ WT_NC, bf16u* __restrict__ WT_PQS,
    bf16u* __restrict__ WT_N1, bf16u* __restrict__ WT_GC,
    float* __restrict__ BIAS_PQS)
{
    int idx = blockIdx.x * 256 + threadIdx.x;
    if (idx < SZ_WTG) {
        int n = idx / 768, k = idx - n * 768;
        WTG_N[idx] = f2b(k < 512 ? Wih_n[(size_t)n * 512 + k] : Whh_n[(size_t)n * 256 + (k - 512)]);
        return;
    }
    idx -= SZ_WTG;
    if (idx < SZ_WTG) {
        int n = idx / 768, k = idx - n * 768;
        WTG_G[idx] = f2b(k < 512 ? Wih_g[(size_t)n * 512 + k] : Whh_g[(size_t)n * 256 + (k - 512)]);
        return;
    }
    idx -= SZ_WTG;
    if (idx < SZ_WTNC) {
        int n = idx / 512, k = idx - n * 512;
        WT_NC[idx] = f2b(ncW[(size_t)k * 256 + n]);
        return;
    }
    idx -= SZ_WTNC;
    if (idx < SZ_WTPQS) {
        int n = idx / 256, k = idx - n * 256;
        float v;
        if (n < 256)      v = Wnn0[(size_t)k * 256 + n];
        else if (n < 512) v = Wnn0[(size_t)(256 + k) * 256 + (n - 256)];
        else              v = Wnn0s[(size_t)k * 256 + (n - 512)];
        WT_PQS[idx] = f2b(v);
        return;
    }
    idx -= SZ_WTPQS;
    if (idx < SZ_WTN1) {
        int n = idx / 1024, k = idx - n * 1024;
        WT_N1[idx] = f2b(Wnn1[(size_t)k * 256 + n]);
        return;
    }
    idx -= SZ_WTN1;
    if (idx < SZ_WTGC) {
        int n = idx / 512, k = idx - n * 512;
        WT_GC[idx] = f2b(gcW[(size_t)k * 256 + n]);
        return;
    }
    idx -= SZ_WTGC;
    if (idx < 768) BIAS_PQS[idx] = (idx < 512) ? 0.f : b_nn0s[idx - 512];
}
#define PREP_MID_TOTAL (2 * SZ_WTG + SZ_WTNC + SZ_WTPQS + SZ_WTN1 + SZ_WTGC + 768)

// pack f32 features -> bf16 rows padded to 160 (4 cols per thread)
__global__ __launch_bounds__(256) void prep_feat16_k(const float* __restrict__ F,
                                                     bf16u* __restrict__ O,
                                                     int rows, int K)
{
    int idx = blockIdx.x * 256 + threadIdx.x;
    if (idx >= rows * 40) return;
    int r = idx / 40, c4 = (idx - r * 40) * 4;
    const float* src = F + (size_t)r * K + c4;
    ushort4 o;
    o.x = (c4 + 0 < K) ? f2b(src[0]) : (bf16u)0;
    o.y = (c4 + 1 < K) ? f2b(src[1]) : (bf16u)0;
    o.z = (c4 + 2 < K) ? f2b(src[2]) : (bf16u)0;
    o.w = (c4 + 3 < K) ? f2b(src[3]) : (bf16u)0;
    *(ushort4*)(O + (size_t)r * 160 + c4) = o;
}

// ---------------- small kernels ----------------
__global__ __launch_bounds__(256) void gather6_bf16_k(const bf16u* __restrict__ msg,
                                                      const int* __restrict__ a2b,
                                                      bf16u* __restrict__ outb)
{
    int idx = blockIdx.x * 256 + threadIdx.x;
    if (idx >= N_ATOMS * (H / 8)) return;
    int na = idx >> 5, c = idx & 31;
    const int* nb = a2b + (size_t)na * MAX_NB;
    float s[8] = {0.f, 0.f, 0.f, 0.f, 0.f, 0.f, 0.f, 0.f};
    #pragma unroll
    for (int j = 0; j < MAX_NB; ++j) {
        uint4 u = *(const uint4*)(msg + (size_t)nb[j] * H + c * 8);
        s[0] += b2f((bf16u)(u.x & 0xFFFFu)); s[1] += b2f((bf16u)(u.x >> 16));
        s[2] += b2f((bf16u)(u.y & 0xFFFFu)); s[3] += b2f((bf16u)(u.y >> 16));
        s[4] += b2f((bf16u)(u.z & 0xFFFFu)); s[5] += b2f((bf16u)(u.z >> 16));
        s[6] += b2f((bf16u)(u.w & 0xFFFFu)); s[7] += b2f((bf16u)(u.w >> 16));
    }
    uint4 o;
    o.x = (unsigned int)f2b(s[0]) | ((unsigned int)f2b(s[1]) << 16);
    o.y = (unsigned int)f2b(s[2]) | ((unsigned int)f2b(s[3]) << 16);
    o.z = (unsigned int)f2b(s[4]) | ((unsigned int)f2b(s[5]) << 16);
    o.w = (unsigned int)f2b(s[6]) | ((unsigned int)f2b(s[7]) << 16);
    *(uint4*)(outb + (size_t)na * H + c * 8) = o;
}

// feat bf16 (BF16F) or f32; h/q_star f32
template<bool BF16F>
__global__ __launch_bounds__(256) void s2s_attn_k(const void* __restrict__ featv,
                                                  const float* __restrict__ h,
                                                  float* __restrict__ q_star, int Nn)
{
    int m = blockIdx.x;
    int t = threadIdx.x;
    int lane = t & 63, wave = t >> 6;
    __shared__ float sc[32];
    const bf16u* fb = (const bf16u*)featv;
    const float* ff = (const float*)featv;
    const size_t fbase = (size_t)m * Nn * H;
    const float* hm = h + (size_t)m * H;
    for (int n = wave; n < Nn; n += 4) {
        float p = 0.f;
        if (BF16F) {
            ushort4 u = *(const ushort4*)(fb + fbase + (size_t)n * H + lane * 4);
            const float4 h4 = *(const float4*)(hm + lane * 4);
            p = b2f(u.x) * h4.x + b2f(u.y) * h4.y + b2f(u.z) * h4.z + b2f(u.w) * h4.w;
        } else {
            const float* fr = ff + fbase + (size_t)n * H;
            #pragma unroll
            for (int u = 0; u < 4; ++u) p += fr[lane * 4 + u] * hm[lane * 4 + u];
        }
        #pragma unroll
        for (int o = 32; o >= 1; o >>= 1) p += __shfl_xor(p, o);
        if (lane == 0) sc[n] = p;
    }
    __syncthreads();
    float mx = -1e30f;
    for (int n = 0; n < Nn; ++n) mx = fmaxf(mx, sc[n]);
    float ssum = 0.f, r = 0.f;
    for (int n = 0; n < Nn; ++n) {
        float a = expf(sc[n] - mx);
        ssum += a;
        float fv = BF16F ? b2f(fb[fbase + (size_t)n * H + t]) : ff[fbase + (size_t)n * H + t];
        r += a * fv;
    }
    r /= ssum;
    q_star[(size_t)m * (2 * H) + t] = hm[t];
    q_star[(size_t)m * (2 * H) + H + t] = r;
}

// X[b,s1,s2,:] from packed PQS [2048][768]: P = +0, Q = +256, SO = +512
__global__ __launch_bounds__(256) void build_x_k(const float* __restrict__ PQS,
                                                 const float* __restrict__ b0,
                                                 float* __restrict__ X)
{
    int idx = blockIdx.x * 256 + threadIdx.x;
    if (idx >= B_RXN * S_STEPS * S_STEPS * H) return;
    int d  = idx & 255;
    int s2 = (idx >> 8) & 3;
    int s1 = (idx >> 10) & 3;
    int b  = idx >> 12;
    float v;
    if (s1 == s2) v = PQS[((size_t)(b * S_STEPS + s1)) * 768 + 512 + d];
    else v = PQS[((size_t)(b * S_STEPS + s1)) * 768 + d]
           + PQS[((size_t)(b * S_STEPS + s2)) * 768 + 256 + d] + b0[d];
    X[idx] = v;
}

// ---------------- launch ----------------
extern "C" void kernel_launch(void* const* d_in, const int* in_sizes, int n_in,
                              void* d_out, int out_size, void* d_ws, size_t ws_size,
                              hipStream_t stream)
{
    const float* f_atoms   = (const float*)d_in[0];
    const float* f_bonds   = (const float*)d_in[1];
    const int*   a2b       = (const int*)d_in[2];
    const int*   b2a       = (const int*)d_in[3];
    const int*   b2revb    = (const int*)d_in[4];
    const float* W_i       = (const float*)d_in[5];
    const float* W_h       = (const float*)d_in[6];
    const float* W_o       = (const float*)d_in[7];
    const float* b_o       = (const float*)d_in[8];
    const float* W_nn0     = (const float*)d_in[9];
    const float* b_nn0     = (const float*)d_in[10];
    const float* W_nn0s    = (const float*)d_in[11];
    const float* b_nn0s    = (const float*)d_in[12];
    const float* W_nn1     = (const float*)d_in[13];
    const float* b_nn1     = (const float*)d_in[14];
    const float* lstm_n_Wih = (const float*)d_in[15];
    const float* lstm_n_Whh = (const float*)d_in[16];
    const float* lstm_n_b   = (const float*)d_in[17];
    const float* node_cond_W = (const float*)d_in[18];
    const float* node_cond_b = (const float*)d_in[19];
    const float* lstm_g_Wih = (const float*)d_in[20];
    const float* lstm_g_Whh = (const float*)d_in[21];
    const float* lstm_g_b   = (const float*)d_in[22];
    const float* graph_cond_W = (const float*)d_in[23];
    const float* graph_cond_b = (const float*)d_in[24];
    float* out = (float*)d_out;

    // ---- workspace layout (~235 MB) ----
    const size_t SZB = (size_t)NBP1 * H * sizeof(bf16u);    // 67,109,376 B
    char* base = (char*)d_ws;
    bf16u* INP  = (bf16u*)(base);                            // [NBP1,H]
    bf16u* MSG  = (bf16u*)(base + SZB);                      // [NBP1,H]
    bf16u* MW   = (bf16u*)(base + 2 * SZB);                  // [NBP1,H]
    bf16u* AMSG = (bf16u*)(base + 3 * SZB);                  // [N_ATOMS,H]
    bf16u* WT_I = (bf16u*)(base + 3 * SZB + 33554432);       // [256][160]
    bf16u* WT_H = (bf16u*)(base + 3 * SZB + 33636352);       // [256][256]
    bf16u* WT_O = (bf16u*)(base + 3 * SZB + 33767424);       // [256][416]
    // aliases:
    bf16u* FB16 = MW;                                        // before 1st MW
    bf16u* FA16 = MW;                                        // after last combine
    bf16u* ATOMH16 = (bf16u*)(base);                         // bf16 feat, alias INP (dead)
    float* SMALL = (float*)(base + SZB);                     // f32 scratch, alias MSG (dead)
    float* HN     = SMALL + 2097152;                         // [2048,256] (ping A)
    float* CN     = SMALL + 2621440;                         // [2048,256] (ping A)
    float* QSTARN = SMALL + 3145728;                         // [2048,512]
    float* MOL    = SMALL + 4194304;                         // [2048,256]
    float* PQS    = SMALL + 4718592;                         // [2048,768]
    float* XBUF   = SMALL + 6291456;                         // [8192,256]
    float* STEPS  = SMALL + 8388608;                         // [2048,256]
    float* HG     = SMALL + 8912896;                         // [512,256] (ping A)
    float* CG     = SMALL + 9043968;                         // [512,256] (ping A)
    float* QSTARG = SMALL + 9175040;                         // [512,512]
    float* HN2    = SMALL + 10485760;                        // [2048,256] (pong B)
    float* CN2    = SMALL + 11010048;                        // [2048,256] (pong B)
    float* HG2    = SMALL + 11534336;                        // [512,256]  (pong B)
    float* CG2    = SMALL + 11665408;                        // [512,256]  (pong B)
    char* sm2 = base + 2 * SZB + 25165824;                   // MW dead zone
    bf16u* WTG_N   = (bf16u*)(sm2);                  // [1024][768]
    bf16u* WTG_G   = (bf16u*)(sm2 + 1572864);        // [1024][768]
    bf16u* WT_NC   = (bf16u*)(sm2 + 3145728);        // [256][512]
    bf16u* WT_PQS  = (bf16u*)(sm2 + 3407872);        // [768][256]
    bf16u* WT_N1   = (bf16u*)(sm2 + 3801088);        // [256][1024]
    bf16u* WT_GC   = (bf16u*)(sm2 + 4325376);        // [256][512]
    float* BIAS_PQS = (float*)(sm2 + 4587520);       // [768]

    dim3 blk(256), blk5(512);
    const int MB_BOND = (NBP1 + 127) / 128;   // 1025
    const int MB_ATOM = N_ATOMS / 128;        // 512
    const int G_GATH = (N_ATOMS * (H / 8) + 255) / 256;
    const int G_COMB = (NBP1 * 32 + 255) / 256;

    // 0. weight + input prep
    prep_wt_k<<<(256 * 160 + 255) / 256, blk, 0, stream>>>(W_i, WT_I, BOND_FDIM, 160);
    prep_wt_k<<<(256 * 256 + 255) / 256, blk, 0, stream>>>(W_h, WT_H, H, 256);
    prep_wto_k<<<(256 * 416 + 255) / 256, blk, 0, stream>>>(W_o, WT_O);
    prep_feat16_k<<<(int)(((size_t)NBP1 * 40 + 255) / 256), blk, 0, stream>>>(
        f_bonds, FB16, NBP1, BOND_FDIM);

    // 1. INP = FB16 @ W_i
    dense_gemm_k<0, false><<<MB_BOND, blk5, 0, stream>>>(
        FB16, nullptr, WT_I, nullptr, INP, NBP1);

    // 2. depth loop
    dense_gemm_k<1, true><<<MB_BOND, blk5, 0, stream>>>(
        INP, nullptr, WT_H, nullptr, MW, NBP1);
    gather6_bf16_k<<<G_GATH, blk, 0, stream>>>(MW, a2b, AMSG);
    combine_k<<<G_COMB, blk, 0, stream>>>(INP, AMSG, MW, b2a, b2revb, MSG);
    dense_gemm_k<1, false><<<MB_BOND, blk5, 0, stream>>>(
        MSG, nullptr, WT_H, nullptr, MW, NBP1);
    gather6_bf16_k<<<G_GATH, blk, 0, stream>>>(MW, a2b, AMSG);
    combine_k<<<G_COMB, blk, 0, stream>>>(INP, AMSG, MW, b2a, b2revb, MSG);

    // 3. nei = gather6(final MSG)
    gather6_bf16_k<<<G_GATH, blk, 0, stream>>>(MSG, a2b, AMSG);

    // 3b. packed f_atoms + merged mid-phase weight prep (MW region dead)
    prep_feat16_k<<<(N_ATOMS * 40 + 255) / 256, blk, 0, stream>>>(
        f_atoms, FA16, N_ATOMS, ATOM_FDIM);
    prep_mid_k<<<(PREP_MID_TOTAL + 255) / 256, blk, 0, stream>>>(
        lstm_n_Wih, lstm_n_Whh, lstm_g_Wih, lstm_g_Whh,
        node_cond_W, W_nn0, W_nn0s, W_nn1, graph_cond_W, b_nn0s,
        WTG_N, WTG_G, WT_NC, WT_PQS, WT_N1, WT_GC, BIAS_PQS);

    // 4. atom_h = relu([f_atoms, nei] @ W_o + b_o) -> ATOMH16 bf16
    dense_gemm_k<2, false><<<MB_ATOM, blk5, 0, stream>>>(
        FA16, AMSG, WT_O, b_o, ATOMH16, N_ATOMS);

    // 5. node Set2Set over [2048, 32, 256]
    {
        lstm0_bcast_k<<<(N_MOLS * H + 255) / 256, blk, 0, stream>>>(lstm_n_b, HN, CN, N_MOLS);
        s2s_attn_k<true><<<N_MOLS, blk, 0, stream>>>(ATOMH16, HN, QSTARN, ATOMS_PER_MOL);
        float *hc = HN, *cc = CN, *hn = HN2, *cn = CN2;
        for (int it = 1; it < N_ITERS; ++it) {
            gates_lstm_k<<<dim3(N_MOLS / 64, 16), blk, 0, stream>>>(
                QSTARN, hc, cc, WTG_N, lstm_n_b, hn, cn, N_MOLS);
            s2s_attn_k<true><<<N_MOLS, blk, 0, stream>>>(ATOMH16, hn, QSTARN, ATOMS_PER_MOL);
            float* t;
            t = hc; hc = hn; hn = t;
            t = cc; cc = cn; cn = t;
        }
    }
    lin64_k<true><<<dim3(N_MOLS / 64, 4), blk, 0, stream>>>(
        QSTARN, 2 * H, 2 * H, QSTARN, 2 * H, WT_NC, 2 * H, node_cond_b, MOL, H, 2 * H);

    // 6. NN attention over steps (fused P|Q|SO GEMM)
    lin64_k<true><<<dim3(N_MOLS / 64, 12), blk, 0, stream>>>(
        MOL, H, H, MOL, H, WT_PQS, H, BIAS_PQS, PQS, 3 * H, H);
    build_x_k<<<(B_RXN * 16 * H) / 256, blk, 0, stream>>>(PQS, b_nn0, XBUF);
    lin64_k<true><<<dim3(N_MOLS / 64, 4), blk, 0, stream>>>(
        XBUF, S_STEPS * H, S_STEPS * H, XBUF, S_STEPS * H, WT_N1, S_STEPS * H, b_nn1,
        STEPS, H, S_STEPS * H);

    // 7. graph Set2Set over [512, 4, 256]
    {
        lstm0_bcast_k<<<(B_RXN * H + 255) / 256, blk, 0, stream>>>(lstm_g_b, HG, CG, B_RXN);
        s2s_attn_k<false><<<B_RXN, blk, 0, stream>>>(STEPS, HG, QSTARG, S_STEPS);
        float *hc = HG, *cc = CG, *hn = HG2, *cn = CG2;
        for (int it = 1; it < N_ITERS; ++it) {
            gates_lstm_k<<<dim3(B_RXN / 64, 16), blk, 0, stream>>>(
                QSTARG, hc, cc, WTG_G, lstm_g_b, hn, cn, B_RXN);
            s2s_attn_k<false><<<B_RXN, blk, 0, stream>>>(STEPS, hn, QSTARG, S_STEPS);
            float* t;
            t = hc; hc = hn; hn = t;
            t = cc; cc = cn; cn = t;
        }
    }

    // 8. out
    lin64_k<true><<<dim3(B_RXN / 64, 4), blk, 0, stream>>>(
        QSTARG, 2 * H, 2 * H, QSTARG, 2 * H, WT_GC, 2 * H, graph_cond_b, out, H, 2 * H);
}